// Round 4
// baseline (350.363 us; speedup 1.0000x reference)
//
#include <hip/hip_runtime.h>
#include <hip/hip_bf16.h>
#include <math.h>

#define B_   16
#define N_   1024
#define H_   4
#define D240 240
#define SC_  57600   // 240*240

typedef unsigned short ushort;
typedef __attribute__((ext_vector_type(8))) short bf16x8;
typedef __attribute__((ext_vector_type(8))) unsigned short u16x8;
typedef __attribute__((ext_vector_type(4))) float f32x4;

__device__ __forceinline__ ushort f2b(float v) {
  __hip_bfloat16 h = __float2bfloat16(v);
  return *reinterpret_cast<ushort*>(&h);
}

__device__ __forceinline__ u16x8 cvt8(float4 a, float4 b) {
  u16x8 w;
  w[0] = f2b(a.x); w[1] = f2b(a.y); w[2] = f2b(a.z); w[3] = f2b(a.w);
  w[4] = f2b(b.x); w[5] = f2b(b.y); w[6] = f2b(b.z); w[7] = f2b(b.w);
  return w;
}

__device__ __forceinline__ void gload16(const void* g, void* s) {
  __builtin_amdgcn_global_load_lds((const __attribute__((address_space(1))) void*)g,
                                   (__attribute__((address_space(3))) void*)s, 16, 0, 0);
}

// Gather address helpers: regrouped-head channel k -> fp32 source pointer.
// (8-element runs never cross segment boundaries: 16/48/112 are 8-aligned.)
__device__ __forceinline__ const float* heads_src(const float* __restrict__ emb_all,
                                                  int b, int n, int h, int k) {
  int soff;
  if (k < 16)       soff = h * 16 + k;
  else if (k < 48)  soff = 64  + h * 32  + (k - 16);
  else if (k < 112) soff = 192 + h * 64  + (k - 48);
  else              soff = 448 + h * 128 + (k - 112);
  return emb_all + ((long)b * N_ + n) * 960 + soff;
}

__device__ __forceinline__ const float* emb_src(const float* __restrict__ e1,
                                                const float* __restrict__ e2,
                                                const float* __restrict__ e3,
                                                const float* __restrict__ e4,
                                                int b, int n, int h, int k, int* stride) {
  if (k < 16)  { *stride = 64;  return e1 + ((long)b * N_ + n) * 64  + h * 16  + k; }
  if (k < 48)  { *stride = 128; return e2 + ((long)b * N_ + n) * 128 + h * 32  + (k - 16); }
  if (k < 112) { *stride = 256; return e3 + ((long)b * N_ + n) * 256 + h * 64  + (k - 48); }
  *stride = 512; return e4 + ((long)b * N_ + n) * 512 + h * 128 + (k - 112);
}

// ---------------------------------------------------------------------------
// conv_weights: Wk_b | Wv_b | Wq_bd (block-diag per head) | Wo_b (col-permuted)
// ---------------------------------------------------------------------------
__global__ __launch_bounds__(256) void conv_weights(
    const float* __restrict__ Wk, const float* __restrict__ Wv,
    const float* __restrict__ q1, const float* __restrict__ q2,
    const float* __restrict__ q3, const float* __restrict__ q4,
    const float* __restrict__ o1, const float* __restrict__ o2,
    const float* __restrict__ o3, const float* __restrict__ o4,
    ushort* __restrict__ wts) {
  long i = (long)blockIdx.x * 256 + threadIdx.x;
  if (i >= 716800) return;
  float v = 0.f;
  if (i < 122880) {
    const float* src = (i < 61440) ? Wk : Wv;
    long j = (i < 61440) ? i : i - 61440;
    int r = j / 256, k = j % 256;
    if (k < 240) v = src[(long)r * 240 + k];
  } else if (i < 368640) {
    long j = i - 122880;
    int h = j / 61440; int rem = j % 61440;
    int r = rem / 256, k = rem % 256;
    int s = r < 16 ? 0 : r < 48 ? 1 : r < 112 ? 2 : 3;
    const int dss[4] = {16, 32, 64, 128};
    const int qf[4]  = {0, 16, 48, 112};
    const float* qs[4] = {q1, q2, q3, q4};
    int d = dss[s], off = qf[s];
    if (k >= off && k < off + d)
      v = qs[s][((long)(h * d + (r - off))) * d + (k - off)];
  } else {
    long j = i - 368640;
    int s = j < 4096 ? 0 : j < 20480 ? 1 : j < 86016 ? 2 : 3;
    const long base[4] = {0, 4096, 20480, 86016};
    const int cs[4] = {64, 128, 256, 512};
    const float* os[4] = {o1, o2, o3, o4};
    long rem = j - base[s];
    int c = cs[s], d = c >> 2;
    int e = rem / c, kk = rem % c;
    v = os[s][(long)e * c + (kk % d) * 4 + kk / d];
  }
  wts[i] = f2b(v);
}

// ---------------------------------------------------------------------------
// core_w_g: A = weight bf16 (gload16, row-clamped vs M), B = fp32 GATHER
// (gmode 0: heads from emb_all; 1: emb from e1..e4), converted to bf16 in
// registers and ds_write'd. C bf16 [M rows (clamped)][1024], ldc given.
// Replaces the heads_b/emb_h staging buffers entirely (bit-identical bf16).
// ---------------------------------------------------------------------------
__device__ __forceinline__ void core_w_g(
    ushort* As, ushort* Bs,
    const ushort* __restrict__ Aw, long lda, int M,
    const float* __restrict__ emb_all,
    const float* __restrict__ e1, const float* __restrict__ e2,
    const float* __restrict__ e3, const float* __restrict__ e4,
    int gmode, int b, int h,
    ushort* __restrict__ C, long ldc, int m0, int n0, int K)
{
  const int tid = threadIdx.x;
  const int l = tid & 63, w = tid >> 6;
  const int wy = w >> 1, wx = w & 1;

  f32x4 acc[4][4];
  #pragma unroll
  for (int i = 0; i < 4; ++i)
    #pragma unroll
    for (int j = 0; j < 4; ++j) acc[i][j] = (f32x4)0.f;

  const int srow = tid >> 2;
  const int skc  = (tid & 3) * 8;
  int ra0 = m0 + srow;      ra0 = ra0 < M ? ra0 : M - 1;
  int ra1 = m0 + srow + 64; ra1 = ra1 < M ? ra1 : M - 1;
  const ushort* a0 = Aw + (long)ra0 * lda + skc;
  const ushort* a1 = Aw + (long)ra1 * lda + skc;
  ushort* lA0 = As + srow * 32 + skc;
  ushort* lA1 = As + (srow + 64) * 32 + skc;
  ushort* lB0 = Bs + srow * 32 + skc;
  ushort* lB1 = Bs + (srow + 64) * 32 + skc;
  const int nrow = n0 + srow;     // gather rows: full 1024 range, no clamp

  const ushort* arp = As + (wy * 64 + (l & 15)) * 32 + (l >> 4) * 8;
  const ushort* brp = Bs + (wx * 64 + (l & 15)) * 32 + (l >> 4) * 8;

  for (int k0 = 0; k0 < K; k0 += 32) {
    __syncthreads();
    gload16(a0 + k0, lA0);
    gload16(a1 + k0, lA1);
    const int k = k0 + skc;
    u16x8 w0, w1;
    if (k < 240) {
      const float* s0; int stride;
      if (gmode == 0) { stride = 960; s0 = heads_src(emb_all, b, nrow, h, k); }
      else            { s0 = emb_src(e1, e2, e3, e4, b, nrow, h, k, &stride); }
      const float* s1 = s0 + (long)64 * stride;
      float4 p0 = *(const float4*)s0, p1 = *(const float4*)(s0 + 4);
      float4 q0 = *(const float4*)s1, q1 = *(const float4*)(s1 + 4);
      w0 = cvt8(p0, p1); w1 = cvt8(q0, q1);
    } else {
      w0 = (u16x8)0; w1 = (u16x8)0;
    }
    *(u16x8*)lB0 = w0;
    *(u16x8*)lB1 = w1;
    __syncthreads();
    bf16x8 af[4], bfr[4];
    #pragma unroll
    for (int i = 0; i < 4; ++i) af[i]  = *(const bf16x8*)(arp + i * 512);
    #pragma unroll
    for (int j = 0; j < 4; ++j) bfr[j] = *(const bf16x8*)(brp + j * 512);
    #pragma unroll
    for (int i = 0; i < 4; ++i)
      #pragma unroll
      for (int j = 0; j < 4; ++j)
        acc[i][j] = __builtin_amdgcn_mfma_f32_16x16x32_bf16(af[i], bfr[j], acc[i][j], 0, 0, 0);
  }

  const int quad = l >> 4, lc = l & 15;
  #pragma unroll
  for (int i = 0; i < 4; ++i) {
    #pragma unroll
    for (int r = 0; r < 4; ++r) {
      int row = m0 + wy * 64 + i * 16 + quad * 4 + r;
      if (row >= M) continue;
      ushort* Cr = C + (long)row * ldc;
      #pragma unroll
      for (int j = 0; j < 4; ++j) {
        int col = n0 + wx * 64 + j * 16 + lc;
        Cr[col] = f2b(acc[i][j][r]);
      }
    }
  }
}

// ---------------------------------------------------------------------------
// core_g_w: A = fp32 gather (heads from emb_all), B = weight bf16 (gload16,
// row-clamped vs Nn, cols zero-padded to Npad). C bf16 [1024][Npad].
// ---------------------------------------------------------------------------
__device__ __forceinline__ void core_g_w(
    ushort* As, ushort* Bs,
    const float* __restrict__ emb_all, int b, int h,
    const ushort* __restrict__ Bw, long ldb, int Nn, int Npad,
    ushort* __restrict__ C, long ldc, int m0, int n0, int K)
{
  const int tid = threadIdx.x;
  const int l = tid & 63, w = tid >> 6;
  const int wy = w >> 1, wx = w & 1;

  f32x4 acc[4][4];
  #pragma unroll
  for (int i = 0; i < 4; ++i)
    #pragma unroll
    for (int j = 0; j < 4; ++j) acc[i][j] = (f32x4)0.f;

  const int srow = tid >> 2;
  const int skc  = (tid & 3) * 8;
  int rb0 = n0 + srow;      rb0 = rb0 < Nn ? rb0 : Nn - 1;
  int rb1 = n0 + srow + 64; rb1 = rb1 < Nn ? rb1 : Nn - 1;
  const ushort* b0 = Bw + (long)rb0 * ldb + skc;
  const ushort* b1 = Bw + (long)rb1 * ldb + skc;
  ushort* lA0 = As + srow * 32 + skc;
  ushort* lA1 = As + (srow + 64) * 32 + skc;
  ushort* lB0 = Bs + srow * 32 + skc;
  ushort* lB1 = Bs + (srow + 64) * 32 + skc;
  const int mrow = m0 + srow;     // gather rows: full 1024 range

  const ushort* arp = As + (wy * 64 + (l & 15)) * 32 + (l >> 4) * 8;
  const ushort* brp = Bs + (wx * 64 + (l & 15)) * 32 + (l >> 4) * 8;

  for (int k0 = 0; k0 < K; k0 += 32) {
    __syncthreads();
    gload16(b0 + k0, lB0);
    gload16(b1 + k0, lB1);
    const int k = k0 + skc;
    u16x8 w0, w1;
    if (k < 240) {
      const float* s0 = heads_src(emb_all, b, mrow, h, k);
      const float* s1 = s0 + (long)64 * 960;
      float4 p0 = *(const float4*)s0, p1 = *(const float4*)(s0 + 4);
      float4 q0 = *(const float4*)s1, q1 = *(const float4*)(s1 + 4);
      w0 = cvt8(p0, p1); w1 = cvt8(q0, q1);
    } else {
      w0 = (u16x8)0; w1 = (u16x8)0;
    }
    *(u16x8*)lA0 = w0;
    *(u16x8*)lA1 = w1;
    __syncthreads();
    bf16x8 af[4], bfr[4];
    #pragma unroll
    for (int i = 0; i < 4; ++i) af[i]  = *(const bf16x8*)(arp + i * 512);
    #pragma unroll
    for (int j = 0; j < 4; ++j) bfr[j] = *(const bf16x8*)(brp + j * 512);
    #pragma unroll
    for (int i = 0; i < 4; ++i)
      #pragma unroll
      for (int j = 0; j < 4; ++j)
        acc[i][j] = __builtin_amdgcn_mfma_f32_16x16x32_bf16(af[i], bfr[j], acc[i][j], 0, 0, 0);
  }

  const int quad = l >> 4, lc = l & 15;
  #pragma unroll
  for (int i = 0; i < 4; ++i) {
    #pragma unroll
    for (int r = 0; r < 4; ++r) {
      int row = m0 + wy * 64 + i * 16 + quad * 4 + r;
      ushort* Cr = C + (long)row * ldc;
      #pragma unroll
      for (int j = 0; j < 4; ++j) {
        int col = n0 + wx * 64 + j * 16 + lc;
        if (col < Nn) Cr[col] = f2b(acc[i][j][r]);
        else if (col < Npad) Cr[col] = 0;
      }
    }
  }
}

// ---------------------------------------------------------------------------
// mfma_proj v2: K/V/Q projections reading fp32 sources DIRECTLY (gather +
// inline bf16 conversion in staging) — conv_inputs pass eliminated.
// ---------------------------------------------------------------------------
__global__ __launch_bounds__(256) void mfma_proj(
    const float* __restrict__ emb_all,
    const float* __restrict__ e1, const float* __restrict__ e2,
    const float* __restrict__ e3, const float* __restrict__ e4,
    const ushort* __restrict__ Wk_b, const ushort* __restrict__ Wv_b,
    const ushort* __restrict__ Wq_bd,
    ushort* __restrict__ Kh_T, ushort* __restrict__ Vh, ushort* __restrict__ Q_T)
{
  __shared__ __align__(16) ushort As[128 * 32];
  __shared__ __align__(16) ushort Bs[128 * 32];
  const int bx = blockIdx.x;

  if (bx < 1024) {
    const int bh = bx >> 4, t = bx & 15;
    const int b = bh >> 2, h = bh & 3;
    core_w_g(As, Bs, Wk_b, 256, 240,
             emb_all, e1, e2, e3, e4, 0, b, h,
             Kh_T + (long)bh * 240 * 1024, 1024,
             (t >> 3) * 128, (t & 7) * 128, 256);
  } else if (bx < 2048) {
    const int local = bx - 1024;
    const int bh = local >> 4, t = local & 15;
    const int b = bh >> 2, h = bh & 3;
    core_g_w(As, Bs, emb_all, b, h,
             Wv_b, 256, 240, 256,
             Vh + (long)bh * 1024 * 256, 256,
             (t >> 1) * 128, (t & 1) * 128, 256);
  } else {
    const int local = bx - 2048;
    const int bh = local >> 4, t = local & 15;
    const int b = bh >> 2, h = bh & 3;
    core_w_g(As, Bs, Wq_bd + h * 61440, 256, 240,
             emb_all, e1, e2, e3, e4, 1, b, h,
             Q_T + (long)bh * 240 * 1024, 1024,
             (t >> 3) * 128, (t & 7) * 128, 256);
  }
}

// ---------------------------------------------------------------------------
// MFMA GEMM (generic, fp32/bf16 out) — used for scores (split-K via grid.z).
// ---------------------------------------------------------------------------
__global__ __launch_bounds__(256) void mfma_abT(
    const ushort* __restrict__ A, long lda, long AsY, long AsZ,
    const ushort* __restrict__ Bm, long ldb, long BsY, long BsZ,
    void* __restrict__ Cv, long ldc, long CsY, long CsZ,
    int M, int Nn, int Npad, int K, float alpha, int c_bf16, int tilesN)
{
  A  += blockIdx.y * AsY + blockIdx.z * AsZ;
  Bm += blockIdx.y * BsY + blockIdx.z * BsZ;

  const int m0 = (blockIdx.x / tilesN) * 128;
  const int n0 = (blockIdx.x % tilesN) * 128;
  const int tid = threadIdx.x;
  const int l = tid & 63, w = tid >> 6;
  const int wy = w >> 1, wx = w & 1;

  __shared__ __align__(16) ushort As[128 * 32];
  __shared__ __align__(16) ushort Bs[128 * 32];

  f32x4 acc[4][4];
  #pragma unroll
  for (int i = 0; i < 4; ++i)
    #pragma unroll
    for (int j = 0; j < 4; ++j) acc[i][j] = (f32x4)0.f;

  const int srow = tid >> 2;
  const int skc  = (tid & 3) * 8;
  int ra0 = m0 + srow;      ra0 = ra0 < M  ? ra0 : M - 1;
  int ra1 = m0 + srow + 64; ra1 = ra1 < M  ? ra1 : M - 1;
  int rb0 = n0 + srow;      rb0 = rb0 < Nn ? rb0 : Nn - 1;
  int rb1 = n0 + srow + 64; rb1 = rb1 < Nn ? rb1 : Nn - 1;
  const ushort* a0 = A  + (long)ra0 * lda + skc;
  const ushort* a1 = A  + (long)ra1 * lda + skc;
  const ushort* b0 = Bm + (long)rb0 * ldb + skc;
  const ushort* b1 = Bm + (long)rb1 * ldb + skc;
  ushort* lA0 = As + srow * 32 + skc;
  ushort* lA1 = As + (srow + 64) * 32 + skc;
  ushort* lB0 = Bs + srow * 32 + skc;
  ushort* lB1 = Bs + (srow + 64) * 32 + skc;

  const ushort* arp = As + (wy * 64 + (l & 15)) * 32 + (l >> 4) * 8;
  const ushort* brp = Bs + (wx * 64 + (l & 15)) * 32 + (l >> 4) * 8;

  for (int k0 = 0; k0 < K; k0 += 32) {
    __syncthreads();
    gload16(a0 + k0, lA0);
    gload16(a1 + k0, lA1);
    gload16(b0 + k0, lB0);
    gload16(b1 + k0, lB1);
    __syncthreads();
    bf16x8 af[4], bfr[4];
    #pragma unroll
    for (int i = 0; i < 4; ++i) af[i]  = *(const bf16x8*)(arp + i * 512);
    #pragma unroll
    for (int j = 0; j < 4; ++j) bfr[j] = *(const bf16x8*)(brp + j * 512);
    #pragma unroll
    for (int i = 0; i < 4; ++i)
      #pragma unroll
      for (int j = 0; j < 4; ++j)
        acc[i][j] = __builtin_amdgcn_mfma_f32_16x16x32_bf16(af[i], bfr[j], acc[i][j], 0, 0, 0);
  }

  const int quad = l >> 4, lc = l & 15;
  if (c_bf16) {
    ushort* C = (ushort*)Cv + blockIdx.y * CsY + blockIdx.z * CsZ;
    #pragma unroll
    for (int i = 0; i < 4; ++i) {
      #pragma unroll
      for (int r = 0; r < 4; ++r) {
        int row = m0 + wy * 64 + i * 16 + quad * 4 + r;
        if (row >= M) continue;
        ushort* Cr = C + (long)row * ldc;
        #pragma unroll
        for (int j = 0; j < 4; ++j) {
          int col = n0 + wx * 64 + j * 16 + lc;
          if (col < Nn) Cr[col] = f2b(acc[i][j][r] * alpha);
          else if (col < Npad) Cr[col] = 0;
        }
      }
    }
  } else {
    float* C = (float*)Cv + blockIdx.y * CsY + blockIdx.z * CsZ;
    #pragma unroll
    for (int i = 0; i < 4; ++i) {
      #pragma unroll
      for (int r = 0; r < 4; ++r) {
        int row = m0 + wy * 64 + i * 16 + quad * 4 + r;
        if (row >= M) continue;
        float* Cr = C + (long)row * ldc;
        #pragma unroll
        for (int j = 0; j < 4; ++j) {
          int col = n0 + wx * 64 + j * 16 + lc;
          if (col < Nn) Cr[col] = acc[i][j][r] * alpha;
        }
      }
    }
  }
}

// ---------------------------------------------------------------------------
// mfma_ctx: fused ctx GEMM. A=Vh[bh] [1024,256], B=P_b[bh] [240,256], K=256.
// Epilogue maps col -> h-interleaved channel in ctx2 [B,N,960] bf16.
// ---------------------------------------------------------------------------
__global__ __launch_bounds__(256) void mfma_ctx(const ushort* __restrict__ V,
                                                const ushort* __restrict__ P,
                                                ushort* __restrict__ ctx2) {
  const int h = blockIdx.y, b = blockIdx.z;
  const ushort* A  = V + (((long)b * H_ + h) * 1024) * 256;
  const ushort* Bm = P + (((long)b * H_ + h) * 240) * 256;

  const int m0 = (blockIdx.x >> 1) * 128;
  const int n0 = (blockIdx.x & 1) * 128;
  const int tid = threadIdx.x;
  const int l = tid & 63, w = tid >> 6;
  const int wy = w >> 1, wx = w & 1;

  __shared__ __align__(16) ushort As[128 * 32];
  __shared__ __align__(16) ushort Bs[128 * 32];

  f32x4 acc[4][4];
  #pragma unroll
  for (int i = 0; i < 4; ++i)
    #pragma unroll
    for (int j = 0; j < 4; ++j) acc[i][j] = (f32x4)0.f;

  const int srow = tid >> 2;
  const int skc  = (tid & 3) * 8;
  int rb0 = n0 + srow;      rb0 = rb0 < 240 ? rb0 : 239;
  int rb1 = n0 + srow + 64; rb1 = rb1 < 240 ? rb1 : 239;
  const ushort* a0 = A  + (long)(m0 + srow) * 256 + skc;
  const ushort* a1 = A  + (long)(m0 + srow + 64) * 256 + skc;
  const ushort* b0 = Bm + (long)rb0 * 256 + skc;
  const ushort* b1 = Bm + (long)rb1 * 256 + skc;
  ushort* lA0 = As + srow * 32 + skc;
  ushort* lA1 = As + (srow + 64) * 32 + skc;
  ushort* lB0 = Bs + srow * 32 + skc;
  ushort* lB1 = Bs + (srow + 64) * 32 + skc;

  const ushort* arp = As + (wy * 64 + (l & 15)) * 32 + (l >> 4) * 8;
  const ushort* brp = Bs + (wx * 64 + (l & 15)) * 32 + (l >> 4) * 8;

  for (int k0 = 0; k0 < 256; k0 += 32) {
    __syncthreads();
    gload16(a0 + k0, lA0);
    gload16(a1 + k0, lA1);
    gload16(b0 + k0, lB0);
    gload16(b1 + k0, lB1);
    __syncthreads();
    bf16x8 af[4], bfr[4];
    #pragma unroll
    for (int i = 0; i < 4; ++i) af[i]  = *(const bf16x8*)(arp + i * 512);
    #pragma unroll
    for (int j = 0; j < 4; ++j) bfr[j] = *(const bf16x8*)(brp + j * 512);
    #pragma unroll
    for (int i = 0; i < 4; ++i)
      #pragma unroll
      for (int j = 0; j < 4; ++j)
        acc[i][j] = __builtin_amdgcn_mfma_f32_16x16x32_bf16(af[i], bfr[j], acc[i][j], 0, 0, 0);
  }

  const int quad = l >> 4, lc = l & 15;
  const int dss[4] = {16, 32, 64, 128};
  const int qf[4]  = {0, 16, 48, 112};
  const int cf[4]  = {0, 64, 192, 448};
  #pragma unroll
  for (int i = 0; i < 4; ++i) {
    #pragma unroll
    for (int r = 0; r < 4; ++r) {
      int row = m0 + wy * 64 + i * 16 + quad * 4 + r;
      ushort* Cr = ctx2 + ((long)b * N_ + row) * 960;
      #pragma unroll
      for (int j = 0; j < 4; ++j) {
        int col = n0 + wx * 64 + j * 16 + lc;
        if (col < 240) {
          int s = col < 16 ? 0 : col < 48 ? 1 : col < 112 ? 2 : 3;
          int chan = cf[s] + h * dss[s] + (col - qf[s]);
          Cr[chan] = f2b(acc[i][j][r]);
        }
      }
    }
  }
}

// ---------------------------------------------------------------------------
// mfma_oproj: grouped out-projection, one dispatch for all 4 scales.
// ---------------------------------------------------------------------------
__global__ __launch_bounds__(256) void mfma_oproj(const ushort* __restrict__ ctx2,
                                                  const ushort* __restrict__ Wo_b,
                                                  float* __restrict__ out) {
  const int bx = blockIdx.x;
  int s = bx < 128 ? 0 : bx < 256 ? 1 : bx < 512 ? 2 : 3;
  const int sbase[4] = {0, 128, 256, 512};
  const int cs_[4]   = {64, 128, 256, 512};
  const int coff_[4] = {0, 64, 192, 448};
  const int wo_[4]   = {0, 4096, 20480, 86016};
  const long oo_[4]  = {0, 1048576, 3145728, 7340032};
  const int c = cs_[s];
  const int nt = (c + 127) >> 7;
  const int local = bx - sbase[s];
  const int m0 = (local / nt) * 128;
  const int n0 = (local % nt) * 128;

  const ushort* A  = ctx2 + coff_[s];
  const ushort* Bm = Wo_b + wo_[s];
  float* C = out + oo_[s];
  const int K = c, Nn = c;

  const int tid = threadIdx.x;
  const int l = tid & 63, w = tid >> 6;
  const int wy = w >> 1, wx = w & 1;

  __shared__ __align__(16) ushort As[128 * 32];
  __shared__ __align__(16) ushort Bs[128 * 32];

  f32x4 acc[4][4];
  #pragma unroll
  for (int i = 0; i < 4; ++i)
    #pragma unroll
    for (int j = 0; j < 4; ++j) acc[i][j] = (f32x4)0.f;

  const int srow = tid >> 2;
  const int skc  = (tid & 3) * 8;
  int rb0 = n0 + srow;      rb0 = rb0 < Nn ? rb0 : Nn - 1;
  int rb1 = n0 + srow + 64; rb1 = rb1 < Nn ? rb1 : Nn - 1;
  const ushort* a0 = A  + (long)(m0 + srow) * 960 + skc;
  const ushort* a1 = A  + (long)(m0 + srow + 64) * 960 + skc;
  const ushort* b0 = Bm + (long)rb0 * c + skc;
  const ushort* b1 = Bm + (long)rb1 * c + skc;
  ushort* lA0 = As + srow * 32 + skc;
  ushort* lA1 = As + (srow + 64) * 32 + skc;
  ushort* lB0 = Bs + srow * 32 + skc;
  ushort* lB1 = Bs + (srow + 64) * 32 + skc;

  const ushort* arp = As + (wy * 64 + (l & 15)) * 32 + (l >> 4) * 8;
  const ushort* brp = Bs + (wx * 64 + (l & 15)) * 32 + (l >> 4) * 8;

  for (int k0 = 0; k0 < K; k0 += 32) {
    __syncthreads();
    gload16(a0 + k0, lA0);
    gload16(a1 + k0, lA1);
    gload16(b0 + k0, lB0);
    gload16(b1 + k0, lB1);
    __syncthreads();
    bf16x8 af[4], bfr[4];
    #pragma unroll
    for (int i = 0; i < 4; ++i) af[i]  = *(const bf16x8*)(arp + i * 512);
    #pragma unroll
    for (int j = 0; j < 4; ++j) bfr[j] = *(const bf16x8*)(brp + j * 512);
    #pragma unroll
    for (int i = 0; i < 4; ++i)
      #pragma unroll
      for (int j = 0; j < 4; ++j)
        acc[i][j] = __builtin_amdgcn_mfma_f32_16x16x32_bf16(af[i], bfr[j], acc[i][j], 0, 0, 0);
  }

  const int quad = l >> 4, lc = l & 15;
  #pragma unroll
  for (int i = 0; i < 4; ++i) {
    #pragma unroll
    for (int r = 0; r < 4; ++r) {
      int row = m0 + wy * 64 + i * 16 + quad * 4 + r;
      float* Cr = C + (long)row * c;
      #pragma unroll
      for (int j = 0; j < 4; ++j) {
        int col = n0 + wx * 64 + j * 16 + lc;
        if (col < Nn) Cr[col] = acc[i][j][r];
      }
    }
  }
}

// ---------------------------------------------------------------------------
// in_stats: per (bh, scale) mean/rstd over d*240 slice; sums split-K partials.
// ---------------------------------------------------------------------------
__global__ __launch_bounds__(256) void in_stats(const float* __restrict__ sc0,
                                                const float* __restrict__ sc1,
                                                float* __restrict__ stats) {
  const int doffs[4] = {0, 16, 48, 112};
  const int dss[4]   = {16, 32, 64, 128};
  const int bh = blockIdx.x, sidx = blockIdx.y;
  const long base = (long)bh * SC_ + doffs[sidx] * D240;
  const float4* A4 = (const float4*)(sc0 + base);
  const float4* B4 = (const float4*)(sc1 + base);
  const int n4 = dss[sidx] * 60;

  float s = 0.f, s2 = 0.f;
  for (int i = threadIdx.x; i < n4; i += 256) {
    float4 a = A4[i], b = B4[i];
    float x0 = a.x + b.x, x1 = a.y + b.y, x2 = a.z + b.z, x3 = a.w + b.w;
    s  += x0 + x1 + x2 + x3;
    s2 += x0 * x0 + x1 * x1 + x2 * x2 + x3 * x3;
  }
  #pragma unroll
  for (int o = 32; o > 0; o >>= 1) { s += __shfl_down(s, o); s2 += __shfl_down(s2, o); }

  __shared__ float wsum[4], wsum2[4];
  const int wave = threadIdx.x >> 6, lane = threadIdx.x & 63;
  if (lane == 0) { wsum[wave] = s; wsum2[wave] = s2; }
  __syncthreads();
  if (threadIdx.x == 0) {
    float n = (float)(n4 * 4);
    float ts = wsum[0] + wsum[1] + wsum[2] + wsum[3];
    float ts2 = wsum2[0] + wsum2[1] + wsum2[2] + wsum2[3];
    float mean = ts / n;
    float var = ts2 / n - mean * mean;
    stats[(bh * 4 + sidx) * 2]     = mean;
    stats[(bh * 4 + sidx) * 2 + 1] = rsqrtf(var + 1e-5f);
  }
}

// ---------------------------------------------------------------------------
// sm_apply: one wave per row; sums split-K partials, normalize + softmax -> P.
// ---------------------------------------------------------------------------
__global__ __launch_bounds__(256) void sm_apply(const float* __restrict__ sc0,
                                                const float* __restrict__ sc1,
                                                const float* __restrict__ stats,
                                                ushort* __restrict__ P) {
  const int bh = blockIdx.y;
  const int row = blockIdx.x * 4 + (threadIdx.x >> 6);
  const int lane = threadIdx.x & 63;
  const int s = row < 16 ? 0 : row < 48 ? 1 : row < 112 ? 2 : 3;
  const float mean = stats[(bh * 4 + s) * 2];
  const float rstd = stats[(bh * 4 + s) * 2 + 1];
  const long base = (long)bh * SC_ + (long)row * D240;
  const float* r0 = sc0 + base;
  const float* r1 = sc1 + base;
  ushort* p = P + ((long)bh * D240 + row) * 256;

  float v[4];
  float mx = -1e30f;
  #pragma unroll
  for (int j = 0; j < 4; ++j) {
    int c = lane + j * 64;
    v[j] = (c < D240) ? (r0[c] + r1[c] - mean) * rstd : -1e30f;
    mx = fmaxf(mx, v[j]);
  }
  #pragma unroll
  for (int o = 32; o > 0; o >>= 1) mx = fmaxf(mx, __shfl_xor(mx, o));
  float sum = 0.f;
  #pragma unroll
  for (int j = 0; j < 4; ++j) {
    int c = lane + j * 64;
    v[j] = (c < D240) ? __expf(v[j] - mx) : 0.f;
    sum += v[j];
  }
  #pragma unroll
  for (int o = 32; o > 0; o >>= 1) sum += __shfl_xor(sum, o);
  float inv = 1.f / sum;
  #pragma unroll
  for (int j = 0; j < 4; ++j) {
    int c = lane + j * 64;
    p[c] = (c < D240) ? f2b(v[j] * inv) : (ushort)0;
  }
}

// ---------------------------------------------------------------------------
// launch
// ---------------------------------------------------------------------------
extern "C" void kernel_launch(void* const* d_in, const int* in_sizes, int n_in,
                              void* d_out, int out_size, void* d_ws, size_t ws_size,
                              hipStream_t stream) {
  const float* emb[4] = {(const float*)d_in[0], (const float*)d_in[1],
                         (const float*)d_in[2], (const float*)d_in[3]};
  const float* emb_all = (const float*)d_in[4];
  const float* Wq[4] = {(const float*)d_in[5], (const float*)d_in[6],
                        (const float*)d_in[7], (const float*)d_in[8]};
  const float* Wk = (const float*)d_in[9];
  const float* Wv = (const float*)d_in[10];
  const float* Wo[4] = {(const float*)d_in[11], (const float*)d_in[12],
                        (const float*)d_in[13], (const float*)d_in[14]};
  float* out = (float*)d_out;
  float* sc0 = (float*)d_out;                  // split-K partial 0
  float* sc1 = (float*)d_out + 64L * SC_;      // split-K partial 1

  ushort* wsb     = (ushort*)d_ws;
  ushort* ctx2    = wsb;               // [B,N,960]
  ushort* P_b     = wsb + 16777216;    // [64,240,256]
  ushort* Q_T     = wsb + 33554432;    // [B,H,240,1024]
  ushort* Kh_T    = wsb + 49283072;    // [B,H,240,1024]
  ushort* Vh      = wsb + 65011712;    // [B,H,1024,256]
  ushort* wts     = wsb + 81788928;    // 716800: Wk_b|Wv_b|Wq_bd|Wo_b
  ushort* Wk_b  = wts;
  ushort* Wv_b  = wts + 61440;
  ushort* Wq_bd = wts + 122880;
  ushort* Wo_b  = wts + 368640;
  float*  stats = (float*)(wsb + 82505728);   // [64][4][2] fp32

  const float alpha_s = 1.0f / sqrtf(960.0f);

  conv_weights<<<dim3(2800), 256, 0, stream>>>(Wk, Wv, Wq[0], Wq[1], Wq[2], Wq[3],
                                               Wo[0], Wo[1], Wo[2], Wo[3], wts);

  // merged K/V/Q projections reading fp32 inputs directly (gather staging)
  mfma_proj<<<dim3(3072), 256, 0, stream>>>(emb_all, emb[0], emb[1], emb[2], emb[3],
                                            Wk_b, Wv_b, Wq_bd, Kh_T, Vh, Q_T);

  // fused scores, split-K x2
  mfma_abT<<<dim3(4, 64, 2), 256, 0, stream>>>(
      Q_T, 1024, 240L * 1024, 512,
      Kh_T, 1024, 240L * 1024, 512,
      sc0, 240, (long)SC_, 64L * SC_,
      240, 240, 240, 512, alpha_s, 0, 2);

  // InstanceNorm stats + softmax apply (summing partials) -> bf16 probs
  in_stats<<<dim3(64, 4), 256, 0, stream>>>(sc0, sc1, stats);
  sm_apply<<<dim3(60, 64), 256, 0, stream>>>(sc0, sc1, stats, P_b);

  // fused ctx
  mfma_ctx<<<dim3(16, H_, B_), 256, 0, stream>>>(Vh, P_b, ctx2);

  // grouped out-proj
  mfma_oproj<<<dim3(1024), 256, 0, stream>>>(ctx2, Wo_b, out);
}

// Round 5
// 345.805 us; speedup vs baseline: 1.0132x; 1.0132x over previous
//
#include <hip/hip_runtime.h>
#include <hip/hip_bf16.h>
#include <math.h>

#define B_   16
#define N_   1024
#define H_   4
#define D240 240

typedef unsigned short ushort;
typedef __attribute__((ext_vector_type(8))) short bf16x8;
typedef __attribute__((ext_vector_type(8))) unsigned short u16x8;
typedef __attribute__((ext_vector_type(4))) float f32x4;

__device__ __forceinline__ ushort f2b(float v) {
  __hip_bfloat16 h = __float2bfloat16(v);
  return *reinterpret_cast<ushort*>(&h);
}

__device__ __forceinline__ u16x8 cvt8(float4 a, float4 b) {
  u16x8 w;
  w[0] = f2b(a.x); w[1] = f2b(a.y); w[2] = f2b(a.z); w[3] = f2b(a.w);
  w[4] = f2b(b.x); w[5] = f2b(b.y); w[6] = f2b(b.z); w[7] = f2b(b.w);
  return w;
}

__device__ __forceinline__ void gload16(const void* g, void* s) {
  __builtin_amdgcn_global_load_lds((const __attribute__((address_space(1))) void*)g,
                                   (__attribute__((address_space(3))) void*)s, 16, 0, 0);
}

// Gather address helpers: regrouped-head channel k -> fp32 source pointer.
__device__ __forceinline__ const float* heads_src(const float* __restrict__ emb_all,
                                                  int b, int n, int h, int k) {
  int soff;
  if (k < 16)       soff = h * 16 + k;
  else if (k < 48)  soff = 64  + h * 32  + (k - 16);
  else if (k < 112) soff = 192 + h * 64  + (k - 48);
  else              soff = 448 + h * 128 + (k - 112);
  return emb_all + ((long)b * N_ + n) * 960 + soff;
}

__device__ __forceinline__ const float* emb_src(const float* __restrict__ e1,
                                                const float* __restrict__ e2,
                                                const float* __restrict__ e3,
                                                const float* __restrict__ e4,
                                                int b, int n, int h, int k, int* stride) {
  if (k < 16)  { *stride = 64;  return e1 + ((long)b * N_ + n) * 64  + h * 16  + k; }
  if (k < 48)  { *stride = 128; return e2 + ((long)b * N_ + n) * 128 + h * 32  + (k - 16); }
  if (k < 112) { *stride = 256; return e3 + ((long)b * N_ + n) * 256 + h * 64  + (k - 48); }
  *stride = 512; return e4 + ((long)b * N_ + n) * 512 + h * 128 + (k - 112);
}

// ---------------------------------------------------------------------------
// conv_weights: Wk_b | Wv_b | Wq_bd (block-diag per head) | Wo_b (col-permuted)
// ---------------------------------------------------------------------------
__global__ __launch_bounds__(256) void conv_weights(
    const float* __restrict__ Wk, const float* __restrict__ Wv,
    const float* __restrict__ q1, const float* __restrict__ q2,
    const float* __restrict__ q3, const float* __restrict__ q4,
    const float* __restrict__ o1, const float* __restrict__ o2,
    const float* __restrict__ o3, const float* __restrict__ o4,
    ushort* __restrict__ wts) {
  long i = (long)blockIdx.x * 256 + threadIdx.x;
  if (i >= 716800) return;
  float v = 0.f;
  if (i < 122880) {
    const float* src = (i < 61440) ? Wk : Wv;
    long j = (i < 61440) ? i : i - 61440;
    int r = j / 256, k = j % 256;
    if (k < 240) v = src[(long)r * 240 + k];
  } else if (i < 368640) {
    long j = i - 122880;
    int h = j / 61440; int rem = j % 61440;
    int r = rem / 256, k = rem % 256;
    int s = r < 16 ? 0 : r < 48 ? 1 : r < 112 ? 2 : 3;
    const int dss[4] = {16, 32, 64, 128};
    const int qf[4]  = {0, 16, 48, 112};
    const float* qs[4] = {q1, q2, q3, q4};
    int d = dss[s], off = qf[s];
    if (k >= off && k < off + d)
      v = qs[s][((long)(h * d + (r - off))) * d + (k - off)];
  } else {
    long j = i - 368640;
    int s = j < 4096 ? 0 : j < 20480 ? 1 : j < 86016 ? 2 : 3;
    const long base[4] = {0, 4096, 20480, 86016};
    const int cs[4] = {64, 128, 256, 512};
    const float* os[4] = {o1, o2, o3, o4};
    long rem = j - base[s];
    int c = cs[s], d = c >> 2;
    int e = rem / c, kk = rem % c;
    v = os[s][(long)e * c + (kk % d) * 4 + kk / d];
  }
  wts[i] = f2b(v);
}

// ---------------------------------------------------------------------------
// core_w_g: A = weight bf16 (gload16, row-clamped vs M), B = fp32 GATHER
// (gmode 0: heads from emb_all; 1: emb from e1..e4), converted to bf16 in
// registers and ds_write'd. C bf16 [M rows (clamped)][1024], ldc given.
// ---------------------------------------------------------------------------
__device__ __forceinline__ void core_w_g(
    ushort* As, ushort* Bs,
    const ushort* __restrict__ Aw, long lda, int M,
    const float* __restrict__ emb_all,
    const float* __restrict__ e1, const float* __restrict__ e2,
    const float* __restrict__ e3, const float* __restrict__ e4,
    int gmode, int b, int h,
    ushort* __restrict__ C, long ldc, int m0, int n0, int K)
{
  const int tid = threadIdx.x;
  const int l = tid & 63, w = tid >> 6;
  const int wy = w >> 1, wx = w & 1;

  f32x4 acc[4][4];
  #pragma unroll
  for (int i = 0; i < 4; ++i)
    #pragma unroll
    for (int j = 0; j < 4; ++j) acc[i][j] = (f32x4)0.f;

  const int srow = tid >> 2;
  const int skc  = (tid & 3) * 8;
  int ra0 = m0 + srow;      ra0 = ra0 < M ? ra0 : M - 1;
  int ra1 = m0 + srow + 64; ra1 = ra1 < M ? ra1 : M - 1;
  const ushort* a0 = Aw + (long)ra0 * lda + skc;
  const ushort* a1 = Aw + (long)ra1 * lda + skc;
  ushort* lA0 = As + srow * 32 + skc;
  ushort* lA1 = As + (srow + 64) * 32 + skc;
  ushort* lB0 = Bs + srow * 32 + skc;
  ushort* lB1 = Bs + (srow + 64) * 32 + skc;
  const int nrow = n0 + srow;

  const ushort* arp = As + (wy * 64 + (l & 15)) * 32 + (l >> 4) * 8;
  const ushort* brp = Bs + (wx * 64 + (l & 15)) * 32 + (l >> 4) * 8;

  for (int k0 = 0; k0 < K; k0 += 32) {
    __syncthreads();
    gload16(a0 + k0, lA0);
    gload16(a1 + k0, lA1);
    const int k = k0 + skc;
    u16x8 w0, w1;
    if (k < 240) {
      const float* s0; int stride;
      if (gmode == 0) { stride = 960; s0 = heads_src(emb_all, b, nrow, h, k); }
      else            { s0 = emb_src(e1, e2, e3, e4, b, nrow, h, k, &stride); }
      const float* s1 = s0 + (long)64 * stride;
      float4 p0 = *(const float4*)s0, p1 = *(const float4*)(s0 + 4);
      float4 q0 = *(const float4*)s1, q1 = *(const float4*)(s1 + 4);
      w0 = cvt8(p0, p1); w1 = cvt8(q0, q1);
    } else {
      w0 = (u16x8)0; w1 = (u16x8)0;
    }
    *(u16x8*)lB0 = w0;
    *(u16x8*)lB1 = w1;
    __syncthreads();
    bf16x8 af[4], bfr[4];
    #pragma unroll
    for (int i = 0; i < 4; ++i) af[i]  = *(const bf16x8*)(arp + i * 512);
    #pragma unroll
    for (int j = 0; j < 4; ++j) bfr[j] = *(const bf16x8*)(brp + j * 512);
    #pragma unroll
    for (int i = 0; i < 4; ++i)
      #pragma unroll
      for (int j = 0; j < 4; ++j)
        acc[i][j] = __builtin_amdgcn_mfma_f32_16x16x32_bf16(af[i], bfr[j], acc[i][j], 0, 0, 0);
  }

  const int quad = l >> 4, lc = l & 15;
  #pragma unroll
  for (int i = 0; i < 4; ++i) {
    #pragma unroll
    for (int r = 0; r < 4; ++r) {
      int row = m0 + wy * 64 + i * 16 + quad * 4 + r;
      if (row >= M) continue;
      ushort* Cr = C + (long)row * ldc;
      #pragma unroll
      for (int j = 0; j < 4; ++j) {
        int col = n0 + wx * 64 + j * 16 + lc;
        Cr[col] = f2b(acc[i][j][r]);
      }
    }
  }
}

// ---------------------------------------------------------------------------
// core_g_w: A = fp32 gather (heads from emb_all), B = weight bf16 (gload16,
// row-clamped vs Nn, cols zero-padded to Npad). C bf16 [1024][Npad].
// ---------------------------------------------------------------------------
__device__ __forceinline__ void core_g_w(
    ushort* As, ushort* Bs,
    const float* __restrict__ emb_all, int b, int h,
    const ushort* __restrict__ Bw, long ldb, int Nn, int Npad,
    ushort* __restrict__ C, long ldc, int m0, int n0, int K)
{
  const int tid = threadIdx.x;
  const int l = tid & 63, w = tid >> 6;
  const int wy = w >> 1, wx = w & 1;

  f32x4 acc[4][4];
  #pragma unroll
  for (int i = 0; i < 4; ++i)
    #pragma unroll
    for (int j = 0; j < 4; ++j) acc[i][j] = (f32x4)0.f;

  const int srow = tid >> 2;
  const int skc  = (tid & 3) * 8;
  int rb0 = n0 + srow;      rb0 = rb0 < Nn ? rb0 : Nn - 1;
  int rb1 = n0 + srow + 64; rb1 = rb1 < Nn ? rb1 : Nn - 1;
  const ushort* b0 = Bw + (long)rb0 * ldb + skc;
  const ushort* b1 = Bw + (long)rb1 * ldb + skc;
  ushort* lA0 = As + srow * 32 + skc;
  ushort* lA1 = As + (srow + 64) * 32 + skc;
  ushort* lB0 = Bs + srow * 32 + skc;
  ushort* lB1 = Bs + (srow + 64) * 32 + skc;
  const int mrow = m0 + srow;

  const ushort* arp = As + (wy * 64 + (l & 15)) * 32 + (l >> 4) * 8;
  const ushort* brp = Bs + (wx * 64 + (l & 15)) * 32 + (l >> 4) * 8;

  for (int k0 = 0; k0 < K; k0 += 32) {
    __syncthreads();
    gload16(b0 + k0, lB0);
    gload16(b1 + k0, lB1);
    const int k = k0 + skc;
    u16x8 w0, w1;
    if (k < 240) {
      const float* s0 = heads_src(emb_all, b, mrow, h, k);
      const float* s1 = s0 + (long)64 * 960;
      float4 p0 = *(const float4*)s0, p1 = *(const float4*)(s0 + 4);
      float4 q0 = *(const float4*)s1, q1 = *(const float4*)(s1 + 4);
      w0 = cvt8(p0, p1); w1 = cvt8(q0, q1);
    } else {
      w0 = (u16x8)0; w1 = (u16x8)0;
    }
    *(u16x8*)lA0 = w0;
    *(u16x8*)lA1 = w1;
    __syncthreads();
    bf16x8 af[4], bfr[4];
    #pragma unroll
    for (int i = 0; i < 4; ++i) af[i]  = *(const bf16x8*)(arp + i * 512);
    #pragma unroll
    for (int j = 0; j < 4; ++j) bfr[j] = *(const bf16x8*)(brp + j * 512);
    #pragma unroll
    for (int i = 0; i < 4; ++i)
      #pragma unroll
      for (int j = 0; j < 4; ++j)
        acc[i][j] = __builtin_amdgcn_mfma_f32_16x16x32_bf16(af[i], bfr[j], acc[i][j], 0, 0, 0);
  }

  const int quad = l >> 4, lc = l & 15;
  #pragma unroll
  for (int i = 0; i < 4; ++i) {
    #pragma unroll
    for (int r = 0; r < 4; ++r) {
      int row = m0 + wy * 64 + i * 16 + quad * 4 + r;
      ushort* Cr = C + (long)row * ldc;
      #pragma unroll
      for (int j = 0; j < 4; ++j) {
        int col = n0 + wx * 64 + j * 16 + lc;
        if (col < Nn) Cr[col] = f2b(acc[i][j][r]);
        else if (col < Npad) Cr[col] = 0;
      }
    }
  }
}

// ---------------------------------------------------------------------------
// mfma_proj: K/V/Q projections reading fp32 sources directly.
// ---------------------------------------------------------------------------
__global__ __launch_bounds__(256) void mfma_proj(
    const float* __restrict__ emb_all,
    const float* __restrict__ e1, const float* __restrict__ e2,
    const float* __restrict__ e3, const float* __restrict__ e4,
    const ushort* __restrict__ Wk_b, const ushort* __restrict__ Wv_b,
    const ushort* __restrict__ Wq_bd,
    ushort* __restrict__ Kh_T, ushort* __restrict__ Vh, ushort* __restrict__ Q_T)
{
  __shared__ __align__(16) ushort As[128 * 32];
  __shared__ __align__(16) ushort Bs[128 * 32];
  const int bx = blockIdx.x;

  if (bx < 1024) {
    const int bh = bx >> 4, t = bx & 15;
    const int b = bh >> 2, h = bh & 3;
    core_w_g(As, Bs, Wk_b, 256, 240,
             emb_all, e1, e2, e3, e4, 0, b, h,
             Kh_T + (long)bh * 240 * 1024, 1024,
             (t >> 3) * 128, (t & 7) * 128, 256);
  } else if (bx < 2048) {
    const int local = bx - 1024;
    const int bh = local >> 4, t = local & 15;
    const int b = bh >> 2, h = bh & 3;
    core_g_w(As, Bs, emb_all, b, h,
             Wv_b, 256, 240, 256,
             Vh + (long)bh * 1024 * 256, 256,
             (t >> 1) * 128, (t & 1) * 128, 256);
  } else {
    const int local = bx - 2048;
    const int bh = local >> 4, t = local & 15;
    const int b = bh >> 2, h = bh & 3;
    core_w_g(As, Bs, Wq_bd + h * 61440, 256, 240,
             emb_all, e1, e2, e3, e4, 1, b, h,
             Q_T + (long)bh * 240 * 1024, 1024,
             (t >> 3) * 128, (t & 7) * 128, 256);
  }
}

// ---------------------------------------------------------------------------
// fused_sm: scores + InstanceNorm + softmax -> P, one block per (scale, bh).
// 512 threads = 8 waves (2 wy x 4 wx). Tile M=128 (d_s rows, clamped) x
// N=256 (240 Kh rows, clamped/masked), K=1024. Whole S slice lives in acc;
// stats/softmax via shfl + LDS reductions. Replaces mfma_abT + in_stats +
// sm_apply (kills 29.5 MB fp32 partial write + 59 MB re-read).
// ---------------------------------------------------------------------------
__global__ __launch_bounds__(512) void fused_sm(const ushort* __restrict__ Q_T,
                                                const ushort* __restrict__ Kh_T,
                                                ushort* __restrict__ P,
                                                float alpha) {
  const int sidx = blockIdx.x, bh = blockIdx.y;
  const int dss[4]   = {16, 32, 64, 128};
  const int doffs[4] = {0, 16, 48, 112};
  const int ds = dss[sidx], doff = doffs[sidx];

  const int tid = threadIdx.x;
  const int l = tid & 63, w = tid >> 6;   // 8 waves
  const int wy = w >> 2, wx = w & 3;      // 2 x 4

  __shared__ __align__(16) ushort As[128 * 32];
  __shared__ __align__(16) ushort Bs[256 * 32];
  __shared__ float red[2][2][64][4];      // [buf][wy][row_local64][wx]
  __shared__ float wred[2][8];

  f32x4 acc[4][4];
  #pragma unroll
  for (int i = 0; i < 4; ++i)
    #pragma unroll
    for (int j = 0; j < 4; ++j) acc[i][j] = (f32x4)0.f;

  const int srow = tid >> 2;              // 0..127
  const int skc  = (tid & 3) * 8;
  const long qbase = (long)bh * 240 * 1024;
  int qa = doff + (srow < ds ? srow : ds - 1);
  const ushort* a0 = Q_T + qbase + (long)qa * 1024 + skc;
  int kb1 = (srow + 128) < 240 ? (srow + 128) : 239;
  const ushort* b0 = Kh_T + qbase + (long)srow * 1024 + skc;
  const ushort* b1 = Kh_T + qbase + (long)kb1 * 1024 + skc;
  ushort* lA0 = As + srow * 32 + skc;
  ushort* lB0 = Bs + srow * 32 + skc;
  ushort* lB1 = Bs + (srow + 128) * 32 + skc;

  const ushort* arp = As + (wy * 64 + (l & 15)) * 32 + (l >> 4) * 8;
  const ushort* brp = Bs + (wx * 64 + (l & 15)) * 32 + (l >> 4) * 8;

  for (int k0 = 0; k0 < 1024; k0 += 32) {
    __syncthreads();
    gload16(a0 + k0, lA0);
    gload16(b0 + k0, lB0);
    gload16(b1 + k0, lB1);
    __syncthreads();
    bf16x8 af[4], bfr[4];
    #pragma unroll
    for (int i = 0; i < 4; ++i) af[i]  = *(const bf16x8*)(arp + i * 512);
    #pragma unroll
    for (int j = 0; j < 4; ++j) bfr[j] = *(const bf16x8*)(brp + j * 512);
    #pragma unroll
    for (int i = 0; i < 4; ++i)
      #pragma unroll
      for (int j = 0; j < 4; ++j)
        acc[i][j] = __builtin_amdgcn_mfma_f32_16x16x32_bf16(af[i], bfr[j], acc[i][j], 0, 0, 0);
  }

  const int quad = l >> 4, lc = l & 15;

  // pass A: alpha-scale + masked block sum/sumsq
  float s1 = 0.f, s2 = 0.f;
  #pragma unroll
  for (int i = 0; i < 4; ++i) {
    #pragma unroll
    for (int j = 0; j < 4; ++j) {
      const int col = wx * 64 + j * 16 + lc;
      #pragma unroll
      for (int r = 0; r < 4; ++r) {
        const int rl = wy * 64 + i * 16 + quad * 4 + r;
        float v = acc[i][j][r] * alpha;
        acc[i][j][r] = v;
        if (rl < ds && col < 240) { s1 += v; s2 += v * v; }
      }
    }
  }
  #pragma unroll
  for (int o = 32; o > 0; o >>= 1) { s1 += __shfl_xor(s1, o); s2 += __shfl_xor(s2, o); }
  if (l == 0) { wred[0][w] = s1; wred[1][w] = s2; }
  __syncthreads();
  float ts = 0.f, ts2 = 0.f;
  #pragma unroll
  for (int ww = 0; ww < 8; ++ww) { ts += wred[0][ww]; ts2 += wred[1][ww]; }
  const float cnt = (float)(ds * 240);
  const float mean = ts / cnt;
  const float var = ts2 / cnt - mean * mean;
  const float rstd = rsqrtf(var + 1e-5f);

  // pass B: normalize; row max (per (i,r)) via quad-shfl + cross-wave LDS
  float rmax[4][4];
  #pragma unroll
  for (int i = 0; i < 4; ++i) {
    #pragma unroll
    for (int r = 0; r < 4; ++r) {
      float m = -1e30f;
      #pragma unroll
      for (int j = 0; j < 4; ++j) {
        const int col = wx * 64 + j * 16 + lc;
        float z = (acc[i][j][r] - mean) * rstd;
        acc[i][j][r] = z;
        if (col < 240) m = fmaxf(m, z);
      }
      m = fmaxf(m, __shfl_xor(m, 1));
      m = fmaxf(m, __shfl_xor(m, 2));
      m = fmaxf(m, __shfl_xor(m, 4));
      m = fmaxf(m, __shfl_xor(m, 8));
      rmax[i][r] = m;
    }
  }
  if (lc == 0) {
    #pragma unroll
    for (int i = 0; i < 4; ++i)
      #pragma unroll
      for (int r = 0; r < 4; ++r)
        red[0][wy][i * 16 + quad * 4 + r][wx] = rmax[i][r];
  }
  __syncthreads();
  #pragma unroll
  for (int i = 0; i < 4; ++i) {
    #pragma unroll
    for (int r = 0; r < 4; ++r) {
      const int rl = i * 16 + quad * 4 + r;
      float m = red[0][wy][rl][0];
      m = fmaxf(m, red[0][wy][rl][1]);
      m = fmaxf(m, red[0][wy][rl][2]);
      m = fmaxf(m, red[0][wy][rl][3]);
      rmax[i][r] = m;
    }
  }

  // exp + row sum
  float rsum[4][4];
  #pragma unroll
  for (int i = 0; i < 4; ++i) {
    #pragma unroll
    for (int r = 0; r < 4; ++r) {
      float sacc = 0.f;
      #pragma unroll
      for (int j = 0; j < 4; ++j) {
        const int col = wx * 64 + j * 16 + lc;
        float e = (col < 240) ? __expf(acc[i][j][r] - rmax[i][r]) : 0.f;
        acc[i][j][r] = e;
        sacc += e;
      }
      sacc += __shfl_xor(sacc, 1);
      sacc += __shfl_xor(sacc, 2);
      sacc += __shfl_xor(sacc, 4);
      sacc += __shfl_xor(sacc, 8);
      rsum[i][r] = sacc;
    }
  }
  if (lc == 0) {
    #pragma unroll
    for (int i = 0; i < 4; ++i)
      #pragma unroll
      for (int r = 0; r < 4; ++r)
        red[1][wy][i * 16 + quad * 4 + r][wx] = rsum[i][r];
  }
  __syncthreads();

  // write P (bf16), zero-padded cols 240..255
  #pragma unroll
  for (int i = 0; i < 4; ++i) {
    #pragma unroll
    for (int r = 0; r < 4; ++r) {
      const int rl = wy * 64 + i * 16 + quad * 4 + r;
      if (rl >= ds) continue;
      const int rli = i * 16 + quad * 4 + r;
      float tot = red[1][wy][rli][0] + red[1][wy][rli][1] +
                  red[1][wy][rli][2] + red[1][wy][rli][3];
      float inv = 1.f / tot;
      ushort* Pr = P + ((long)bh * 240 + doff + rl) * 256;
      #pragma unroll
      for (int j = 0; j < 4; ++j) {
        const int col = wx * 64 + j * 16 + lc;
        Pr[col] = (col < 240) ? f2b(acc[i][j][r] * inv) : (ushort)0;
      }
    }
  }
}

// ---------------------------------------------------------------------------
// mfma_ctx: fused ctx GEMM. A=Vh[bh] [1024,256], B=P_b[bh] [240,256], K=256.
// Epilogue maps col -> h-interleaved channel in ctx2 [B,N,960] bf16.
// ---------------------------------------------------------------------------
__global__ __launch_bounds__(256) void mfma_ctx(const ushort* __restrict__ V,
                                                const ushort* __restrict__ P,
                                                ushort* __restrict__ ctx2) {
  const int h = blockIdx.y, b = blockIdx.z;
  const ushort* A  = V + (((long)b * H_ + h) * 1024) * 256;
  const ushort* Bm = P + (((long)b * H_ + h) * 240) * 256;

  const int m0 = (blockIdx.x >> 1) * 128;
  const int n0 = (blockIdx.x & 1) * 128;
  const int tid = threadIdx.x;
  const int l = tid & 63, w = tid >> 6;
  const int wy = w >> 1, wx = w & 1;

  __shared__ __align__(16) ushort As[128 * 32];
  __shared__ __align__(16) ushort Bs[128 * 32];

  f32x4 acc[4][4];
  #pragma unroll
  for (int i = 0; i < 4; ++i)
    #pragma unroll
    for (int j = 0; j < 4; ++j) acc[i][j] = (f32x4)0.f;

  const int srow = tid >> 2;
  const int skc  = (tid & 3) * 8;
  int rb0 = n0 + srow;      rb0 = rb0 < 240 ? rb0 : 239;
  int rb1 = n0 + srow + 64; rb1 = rb1 < 240 ? rb1 : 239;
  const ushort* a0 = A  + (long)(m0 + srow) * 256 + skc;
  const ushort* a1 = A  + (long)(m0 + srow + 64) * 256 + skc;
  const ushort* b0 = Bm + (long)rb0 * 256 + skc;
  const ushort* b1 = Bm + (long)rb1 * 256 + skc;
  ushort* lA0 = As + srow * 32 + skc;
  ushort* lA1 = As + (srow + 64) * 32 + skc;
  ushort* lB0 = Bs + srow * 32 + skc;
  ushort* lB1 = Bs + (srow + 64) * 32 + skc;

  const ushort* arp = As + (wy * 64 + (l & 15)) * 32 + (l >> 4) * 8;
  const ushort* brp = Bs + (wx * 64 + (l & 15)) * 32 + (l >> 4) * 8;

  for (int k0 = 0; k0 < 256; k0 += 32) {
    __syncthreads();
    gload16(a0 + k0, lA0);
    gload16(a1 + k0, lA1);
    gload16(b0 + k0, lB0);
    gload16(b1 + k0, lB1);
    __syncthreads();
    bf16x8 af[4], bfr[4];
    #pragma unroll
    for (int i = 0; i < 4; ++i) af[i]  = *(const bf16x8*)(arp + i * 512);
    #pragma unroll
    for (int j = 0; j < 4; ++j) bfr[j] = *(const bf16x8*)(brp + j * 512);
    #pragma unroll
    for (int i = 0; i < 4; ++i)
      #pragma unroll
      for (int j = 0; j < 4; ++j)
        acc[i][j] = __builtin_amdgcn_mfma_f32_16x16x32_bf16(af[i], bfr[j], acc[i][j], 0, 0, 0);
  }

  const int quad = l >> 4, lc = l & 15;
  const int dss[4] = {16, 32, 64, 128};
  const int qf[4]  = {0, 16, 48, 112};
  const int cf[4]  = {0, 64, 192, 448};
  #pragma unroll
  for (int i = 0; i < 4; ++i) {
    #pragma unroll
    for (int r = 0; r < 4; ++r) {
      int row = m0 + wy * 64 + i * 16 + quad * 4 + r;
      ushort* Cr = ctx2 + ((long)b * N_ + row) * 960;
      #pragma unroll
      for (int j = 0; j < 4; ++j) {
        int col = n0 + wx * 64 + j * 16 + lc;
        if (col < 240) {
          int s = col < 16 ? 0 : col < 48 ? 1 : col < 112 ? 2 : 3;
          int chan = cf[s] + h * dss[s] + (col - qf[s]);
          Cr[chan] = f2b(acc[i][j][r]);
        }
      }
    }
  }
}

// ---------------------------------------------------------------------------
// mfma_oproj: grouped out-projection, one dispatch for all 4 scales.
// ---------------------------------------------------------------------------
__global__ __launch_bounds__(256) void mfma_oproj(const ushort* __restrict__ ctx2,
                                                  const ushort* __restrict__ Wo_b,
                                                  float* __restrict__ out) {
  const int bx = blockIdx.x;
  int s = bx < 128 ? 0 : bx < 256 ? 1 : bx < 512 ? 2 : 3;
  const int sbase[4] = {0, 128, 256, 512};
  const int cs_[4]   = {64, 128, 256, 512};
  const int coff_[4] = {0, 64, 192, 448};
  const int wo_[4]   = {0, 4096, 20480, 86016};
  const long oo_[4]  = {0, 1048576, 3145728, 7340032};
  const int c = cs_[s];
  const int nt = (c + 127) >> 7;
  const int local = bx - sbase[s];
  const int m0 = (local / nt) * 128;
  const int n0 = (local % nt) * 128;

  const ushort* A  = ctx2 + coff_[s];
  const ushort* Bm = Wo_b + wo_[s];
  float* C = out + oo_[s];
  const int K = c, Nn = c;

  const int tid = threadIdx.x;
  const int l = tid & 63, w = tid >> 6;
  const int wy = w >> 1, wx = w & 1;

  __shared__ __align__(16) ushort As[128 * 32];
  __shared__ __align__(16) ushort Bs[128 * 32];

  f32x4 acc[4][4];
  #pragma unroll
  for (int i = 0; i < 4; ++i)
    #pragma unroll
    for (int j = 0; j < 4; ++j) acc[i][j] = (f32x4)0.f;

  const int srow = tid >> 2;
  const int skc  = (tid & 3) * 8;
  int rb0 = n0 + srow;      rb0 = rb0 < Nn ? rb0 : Nn - 1;
  int rb1 = n0 + srow + 64; rb1 = rb1 < Nn ? rb1 : Nn - 1;
  const ushort* a0 = A  + (long)(m0 + srow) * 960 + skc;
  const ushort* a1 = A  + (long)(m0 + srow + 64) * 960 + skc;
  const ushort* b0 = Bm + (long)rb0 * c + skc;
  const ushort* b1 = Bm + (long)rb1 * c + skc;
  ushort* lA0 = As + srow * 32 + skc;
  ushort* lA1 = As + (srow + 64) * 32 + skc;
  ushort* lB0 = Bs + srow * 32 + skc;
  ushort* lB1 = Bs + (srow + 64) * 32 + skc;

  const ushort* arp = As + (wy * 64 + (l & 15)) * 32 + (l >> 4) * 8;
  const ushort* brp = Bs + (wx * 64 + (l & 15)) * 32 + (l >> 4) * 8;

  for (int k0 = 0; k0 < K; k0 += 32) {
    __syncthreads();
    gload16(a0 + k0, lA0);
    gload16(a1 + k0, lA1);
    gload16(b0 + k0, lB0);
    gload16(b1 + k0, lB1);
    __syncthreads();
    bf16x8 af[4], bfr[4];
    #pragma unroll
    for (int i = 0; i < 4; ++i) af[i]  = *(const bf16x8*)(arp + i * 512);
    #pragma unroll
    for (int j = 0; j < 4; ++j) bfr[j] = *(const bf16x8*)(brp + j * 512);
    #pragma unroll
    for (int i = 0; i < 4; ++i)
      #pragma unroll
      for (int j = 0; j < 4; ++j)
        acc[i][j] = __builtin_amdgcn_mfma_f32_16x16x32_bf16(af[i], bfr[j], acc[i][j], 0, 0, 0);
  }

  const int quad = l >> 4, lc = l & 15;
  #pragma unroll
  for (int i = 0; i < 4; ++i) {
    #pragma unroll
    for (int r = 0; r < 4; ++r) {
      int row = m0 + wy * 64 + i * 16 + quad * 4 + r;
      float* Cr = C + (long)row * c;
      #pragma unroll
      for (int j = 0; j < 4; ++j) {
        int col = n0 + wx * 64 + j * 16 + lc;
        if (col < Nn) Cr[col] = acc[i][j][r];
      }
    }
  }
}

// ---------------------------------------------------------------------------
// launch
// ---------------------------------------------------------------------------
extern "C" void kernel_launch(void* const* d_in, const int* in_sizes, int n_in,
                              void* d_out, int out_size, void* d_ws, size_t ws_size,
                              hipStream_t stream) {
  const float* emb[4] = {(const float*)d_in[0], (const float*)d_in[1],
                         (const float*)d_in[2], (const float*)d_in[3]};
  const float* emb_all = (const float*)d_in[4];
  const float* Wq[4] = {(const float*)d_in[5], (const float*)d_in[6],
                        (const float*)d_in[7], (const float*)d_in[8]};
  const float* Wk = (const float*)d_in[9];
  const float* Wv = (const float*)d_in[10];
  const float* Wo[4] = {(const float*)d_in[11], (const float*)d_in[12],
                        (const float*)d_in[13], (const float*)d_in[14]};
  float* out = (float*)d_out;

  ushort* wsb     = (ushort*)d_ws;
  ushort* ctx2    = wsb;               // [B,N,960]
  ushort* P_b     = wsb + 16777216;    // [64,240,256]
  ushort* Q_T     = wsb + 33554432;    // [B,H,240,1024]
  ushort* Kh_T    = wsb + 49283072;    // [B,H,240,1024]
  ushort* Vh      = wsb + 65011712;    // [B,H,1024,256]
  ushort* wts     = wsb + 81788928;    // 716800: Wk_b|Wv_b|Wq_bd|Wo_b
  ushort* Wk_b  = wts;
  ushort* Wv_b  = wts + 61440;
  ushort* Wq_bd = wts + 122880;
  ushort* Wo_b  = wts + 368640;

  const float alpha_s = 1.0f / sqrtf(960.0f);

  conv_weights<<<dim3(2800), 256, 0, stream>>>(Wk, Wv, Wq[0], Wq[1], Wq[2], Wq[3],
                                               Wo[0], Wo[1], Wo[2], Wo[3], wts);

  // merged K/V/Q projections reading fp32 inputs directly (gather staging)
  mfma_proj<<<dim3(3072), 256, 0, stream>>>(emb_all, emb[0], emb[1], emb[2], emb[3],
                                            Wk_b, Wv_b, Wq_bd, Kh_T, Vh, Q_T);

  // fused scores + InstanceNorm + softmax -> P (replaces abT/in_stats/sm_apply)
  fused_sm<<<dim3(4, 64), 512, 0, stream>>>(Q_T, Kh_T, P_b, alpha_s);

  // fused ctx
  mfma_ctx<<<dim3(16, H_, B_), 256, 0, stream>>>(Vh, P_b, ctx2);

  // grouped out-proj
  mfma_oproj<<<dim3(1024), 256, 0, stream>>>(ctx2, Wo_b, out);
}